// Round 17
// baseline (3298.260 us; speedup 1.0000x reference)
//
#include <hip/hip_runtime.h>

// ---------------- problem constants ----------------
#define BATCH 64
#define SLEN  512
#define EDIM  512
#define HDIM  1024
#define NBLK  256
#define HALF  128                // blocks per layer group
#define ZR    32                 // z-rows per block = 4 gates x 8 h-cols
#define ZST   68                 // zbuf batch-row stride (2 nt-partials of 34)
#define HSLOT 65536              // bytes per h slot (64 x 1024 e5m2)
#define XROWB 512                // xe row bytes (512 e5m2)
#define RING  8                  // fallback ring depth

#define XE_BYTES ((size_t)SLEN * BATCH * XROWB)         // 16 MiB
#define HBUF_BIG ((size_t)SLEN * HSLOT)                 // 32 MiB per layer
#define HBUF_SML ((size_t)RING * HSLOT)                 // 512 KiB per layer

typedef _Float16 f16x8 __attribute__((ext_vector_type(8)));
typedef float  f32x4  __attribute__((ext_vector_type(4)));
typedef unsigned u32x4 __attribute__((ext_vector_type(4)));
typedef unsigned u32x2 __attribute__((ext_vector_type(2)));

__device__ __forceinline__ float sigm(float x) { return 1.0f / (1.0f + __expf(-x)); }
__device__ __forceinline__ float tanhfast(float x) {
  float e = __expf(-2.0f * __builtin_fabsf(x));
  float r = (1.0f - e) / (1.0f + e);
  return x < 0.0f ? -r : r;
}

// f32 -> e5m2 byte (via f16, round mantissa-half-up)
__device__ __forceinline__ unsigned enc_e5m2(float v) {
  unsigned short hb = __builtin_bit_cast(unsigned short, (_Float16)v);
  return ((unsigned)hb + 0x80u) >> 8;
}

// 4 e5m2 bytes (one dword) -> 2 dwords of f16 pairs (byte<<8 expand via v_perm)
__device__ __forceinline__ void dec4(unsigned w, unsigned &lo, unsigned &hi) {
  lo = __builtin_amdgcn_perm(w, 0u, 0x05000400u);   // [0,b0, 0,b1]
  hi = __builtin_amdgcn_perm(w, 0u, 0x07000600u);   // [0,b2, 0,b3]
}

// 16 e5m2 bytes -> two f16x8 fragments (bytes 0-7 = k..k+8 half0, 8-15 = half1)
__device__ __forceinline__ void dec16(u32x4 d, f16x8 &fa, f16x8 &fb) {
  union { unsigned u[4]; f16x8 v; } A, B;
  dec4(d[0], A.u[0], A.u[1]); dec4(d[1], A.u[2], A.u[3]);
  dec4(d[2], B.u[0], B.u[1]); dec4(d[3], B.u[2], B.u[3]);
  fa = A.v; fb = B.v;
}

// 8B write-through store (L3-visible after vmcnt drain; never dirty in L2)
__device__ __forceinline__ void st8_wt(unsigned char* p, unsigned d0, unsigned d1) {
  u32x2 v = {d0, d1};
  asm volatile("global_store_dwordx2 %0, %1, off sc0 sc1" :: "v"(p), "v"(v) : "memory");
}

// 16B loads: BIG = normal (L2-multicast); ring mode = L2-bypassing atomics
__device__ __forceinline__ u32x4 ald16b(const unsigned char* p) {
  union { unsigned long long q[2]; u32x4 v; } u;
  u.q[0] = __hip_atomic_load((const unsigned long long*)p,       __ATOMIC_RELAXED, __HIP_MEMORY_SCOPE_AGENT);
  u.q[1] = __hip_atomic_load((const unsigned long long*)(p + 8), __ATOMIC_RELAXED, __HIP_MEMORY_SCOPE_AGENT);
  return u.v;
}
template<int BIG>
__device__ __forceinline__ u32x4 hload16(const unsigned char* p) {
  if constexpr (BIG) return *(const u32x4*)p;
  else return ald16b(p);
}

// Quarter wait: producers [base, base+32) only — a wave proceeds as soon as
// ITS k-quarter's 32 producers have flagged (streaming-K; no global max-128).
__device__ __forceinline__ void quarter_wait(const int* f, int base, int target) {
  if (target <= 0) return;
  const int l = threadIdx.x & 31;      // lanes 32-63 duplicate lanes 0-31
  int tries = 0;
  while (true) {
    int v = __hip_atomic_load(f + base + l, __ATOMIC_RELAXED, __HIP_MEMORY_SCOPE_AGENT);
    if (__all(v >= target)) return;
    __builtin_amdgcn_s_sleep(1);
    if (++tries > (1 << 21)) return;   // anti-hang safety net
  }
}

// Block-level wait over all 128 flags (ring-mode anti-dep path only)
__device__ __forceinline__ void block_wait(const int* f, int target, int* gate) {
  if (target <= 0) return;
  if ((threadIdx.x >> 6) == 0) {
    if (__hip_atomic_load(gate, __ATOMIC_RELAXED, __HIP_MEMORY_SCOPE_WORKGROUP) < target) {
      const int l = threadIdx.x & 63;
      int tries = 0;
      while (true) {
        int v0 = __hip_atomic_load(f + l,      __ATOMIC_RELAXED, __HIP_MEMORY_SCOPE_AGENT);
        int v1 = __hip_atomic_load(f + l + 64, __ATOMIC_RELAXED, __HIP_MEMORY_SCOPE_AGENT);
        if (__all((v0 >= target) && (v1 >= target))) break;
        __builtin_amdgcn_s_sleep(1);
        if (++tries > (1 << 21)) break;
      }
      if (l == 0)
        __hip_atomic_fetch_max(gate, target, __ATOMIC_RELEASE, __HIP_MEMORY_SCOPE_WORKGROUP);
    }
  } else {
    int tries = 0;
    while (__hip_atomic_load(gate, __ATOMIC_ACQUIRE, __HIP_MEMORY_SCOPE_WORKGROUP) < target) {
      __builtin_amdgcn_s_sleep(1);
      if (++tries > (1 << 21)) break;
    }
  }
}

// ---- xe = e5m2(emb[x]) laid out [t][b][512B], 64-col-group permuted ----
__global__ void xe_gather(const int* __restrict__ x, const float* __restrict__ emb,
                          unsigned char* __restrict__ xe) {
  int g = blockIdx.x * blockDim.x + threadIdx.x;
  if (g >= SLEN * BATCH * (EDIM / 8)) return;
  int e8 = g & 63, bt = g >> 6;
  int b = bt & 63, t = bt >> 6;
  int tok = x[b * SLEN + t];
  const float* er = emb + (size_t)tok * EDIM + e8 * 8;
  f32x4 v0 = *(const f32x4*)er, v1 = *(const f32x4*)(er + 4);
  unsigned d0 = enc_e5m2(v0[0]) | (enc_e5m2(v0[1]) << 8) | (enc_e5m2(v0[2]) << 16) | (enc_e5m2(v0[3]) << 24);
  unsigned d1 = enc_e5m2(v1[0]) | (enc_e5m2(v1[1]) << 8) | (enc_e5m2(v1[2]) << 16) | (enc_e5m2(v1[3]) << 24);
  int pb = (e8 >> 3) * 64 + (e8 & 3) * 16 + ((e8 >> 2) & 1) * 8;
  *(u32x2*)(xe + ((size_t)t * BATCH + b) * XROWB + pb) = (u32x2){d0, d1};
}

#define MFMA(a, b, c) __builtin_amdgcn_mfma_f32_16x16x32_f16(a, b, c, 0, 0, 0)
// fragment-major B: fragment (t, kg) at ((t*64+kg)*64 + lane)*16 — a wave's
// read is one contiguous 1KB burst (R14-measured: conflicts 2.5e8 -> 1.7e7).
#define LDSBF(t, kg) (*(const f16x8*)(&Ws[(size_t)((((t) * 64 + (kg)) * 64 + lane)) * 16]))

// Persistent skewed 2-layer LSTM. e5m2 activations, f16 fragment-major weights.
// R17: STREAMING-K — h-GEMMs consume k-quarters as their 32 producers flag
// (overlaps straggler tail with compute); geometry/epilogue/layout = R14/R16.
template<int BIG>
__global__ __launch_bounds__(512, 2) void lstm_persistent(
    const int* __restrict__ x, const float* __restrict__ emb,
    const float* __restrict__ Wx0, const float* __restrict__ bx0,
    const float* __restrict__ Wh0, const float* __restrict__ bh0,
    const float* __restrict__ Wx1, const float* __restrict__ bx1,
    const float* __restrict__ Wh1, const float* __restrict__ bh1,
    const unsigned char* __restrict__ xe, int use_xe,
    unsigned char* h0buf, unsigned char* h1buf, int* f0, int* f1)
{
  __shared__ __align__(16) unsigned char Ws[2 * 64 * 64 * 16];  // 128 KiB
  __shared__ float zbuf[BATCH * ZST];                           // 17 KiB
  __shared__ float bias[ZR];
  __shared__ int gateF0, gateF1;

  const int tid   = threadIdx.x;
  const int wg    = blockIdx.x;
  const int layer = wg >> 7;
  const int sub   = wg & (HALF - 1);

  if (tid == 0) { gateF0 = 0; gateF1 = 0; }

  // ---- stage weights into fragment-major LDS (linear 16B writes) ----
  {
    const int KG = layer ? 64 : 48;          // k-groups of 32 f16 elems
    for (int idx = tid; idx < 2 * KG * 64; idx += 512) {
      int t  = idx / (KG * 64);
      int r  = idx - t * (KG * 64);
      int kg = r >> 6, ln = r & 63;
      int n  = t * 16 + (ln & 15);           // z-col 0..31
      int grow = (n >> 3) * HDIM + sub * 8 + (n & 7);
      int k  = kg * 32 + (ln >> 4) * 8;
      const float* src;
      if (layer == 0) src = (k < EDIM) ? (Wx0 + (size_t)grow * EDIM + k)
                                       : (Wh0 + (size_t)grow * HDIM + (k - EDIM));
      else            src = (k < HDIM) ? (Wx1 + (size_t)grow * HDIM + k)
                                       : (Wh1 + (size_t)grow * HDIM + (k - HDIM));
      f32x4 v0 = *(const f32x4*)src, v1 = *(const f32x4*)(src + 4);
      f16x8 o = { (_Float16)v0[0], (_Float16)v0[1], (_Float16)v0[2], (_Float16)v0[3],
                  (_Float16)v1[0], (_Float16)v1[1], (_Float16)v1[2], (_Float16)v1[3] };
      *(f16x8*)(&Ws[(size_t)((t * 64 + kg) * 64 + ln) * 16]) = o;
    }
    if (tid < ZR) {
      int grow = (tid >> 3) * HDIM + sub * 8 + (tid & 7);
      bias[tid] = layer ? (bx1[grow] + bh1[grow]) : (bx0[grow] + bh0[grow]);
    }
  }
  __syncthreads();

  const int lane = tid & 63, wave = tid >> 6;
  const int mrow = lane & 15;
  const int q    = lane >> 4;
  const int mt   = wave >> 1, nt = wave & 1;   // 4 batch tiles x 2 contiguous K-halves
  const int brow = mt * 16 + mrow;
  const int bg = tid >> 3, jl = tid & 7;
  const int zrow = mt * 16 + q * 4;
  const int pbase = (sub >> 3) * 64 + (sub & 3) * 16 + ((sub >> 2) & 1) * 8;

  float cst = 0.0f;

#define SLOTB(s) ((size_t)(BIG ? (s) : ((s) & (RING - 1))) * HSLOT)

#define ZWRITE()                                                                  \
  do {                                                                            \
    _Pragma("unroll")                                                             \
    for (int r = 0; r < 4; ++r) {                                                 \
      zbuf[(zrow + r) * ZST + nt * 34 + mrow]      = acc0[r];                     \
      zbuf[(zrow + r) * ZST + nt * 34 + 16 + mrow] = acc1[r];                     \
    }                                                                             \
  } while (0)

#define EPILOGUE(hdst, slotExpr)                                                  \
  do {                                                                            \
    float zf = zbuf[bg*ZST +      jl] + zbuf[bg*ZST + 34 +      jl] + bias[     jl]; \
    float zi = zbuf[bg*ZST +  8 + jl] + zbuf[bg*ZST + 34 +  8 + jl] + bias[ 8 + jl]; \
    float zg = zbuf[bg*ZST + 16 + jl] + zbuf[bg*ZST + 34 + 16 + jl] + bias[16 + jl]; \
    float zo = zbuf[bg*ZST + 24 + jl] + zbuf[bg*ZST + 34 + 24 + jl] + bias[24 + jl]; \
    float fg = sigm(zf), ig = sigm(zi), gg = tanhfast(zg), og = sigm(zo);         \
    cst = fg * cst + ig * gg;                                                     \
    unsigned by = enc_e5m2(og * tanhfast(cst));                                   \
    unsigned w0 = by | (((unsigned)__shfl_xor((int)by, 1, 64) & 0xFFu) << 8);     \
    w0 |= ((unsigned)__shfl_xor((int)w0, 2, 64) & 0xFFFFu) << 16;                 \
    unsigned dd1 = (unsigned)__shfl_xor((int)w0, 4, 64);                          \
    if (jl == 0)                                                                  \
      st8_wt(hdst + (slotExpr) + (size_t)bg * 1024 + pbase, w0, dd1);             \
    asm volatile("s_waitcnt vmcnt(0)" ::: "memory");                              \
  } while (0)

// streamed h-GEMM over this wave's 2 k-quarters: per quarter, wait only its
// 32 producers, then 4 loads + decode + 16 MFMA.
#define HPART_STREAM(fl, target, hp, kgbase)                                      \
  do {                                                                            \
    _Pragma("unroll")                                                             \
    for (int qq = 0; qq < 2; ++qq) {                                              \
      quarter_wait(fl, (2 * nt + qq) * 32, target);                               \
      _Pragma("unroll")                                                           \
      for (int g = qq * 4; g < qq * 4 + 4; ++g) {                                 \
        f16x8 fa, fb; dec16(hload16<BIG>((hp) + g * 64), fa, fb);                 \
        const int kg = (kgbase) + g * 2;                                          \
        acc0 = MFMA(fa, LDSBF(0, kg), acc0);     acc1 = MFMA(fa, LDSBF(1, kg), acc1); \
        acc0 = MFMA(fb, LDSBF(0, kg + 1), acc0); acc1 = MFMA(fb, LDSBF(1, kg + 1), acc1); \
      }                                                                           \
    }                                                                             \
  } while (0)

  if (layer == 0) {
    for (int s = 0; s < SLEN; ++s) {
      f32x4 acc0 = {0.f,0.f,0.f,0.f}, acc1 = {0.f,0.f,0.f,0.f};
      // --- xe part: no cross-block dep, runs before any wait ---
      if (use_xe) {
        const unsigned char* aX = xe + ((size_t)s * BATCH + brow) * XROWB + nt * 256 + q * 16;
        #pragma unroll
        for (int g = 0; g < 4; ++g) {
          f16x8 fa, fb; dec16(*(const u32x4*)(aX + g * 64), fa, fb);
          const int kg = nt * 8 + g * 2;
          acc0 = MFMA(fa, LDSBF(0, kg), acc0);     acc1 = MFMA(fa, LDSBF(1, kg), acc1);
          acc0 = MFMA(fb, LDSBF(0, kg + 1), acc0); acc1 = MFMA(fb, LDSBF(1, kg + 1), acc1);
        }
      } else {
        const int tok = x[brow * SLEN + s];
        const float* erow = emb + (size_t)tok * EDIM;
        #pragma unroll
        for (int g = 0; g < 4; ++g) {
          const int k = nt * 256 + g * 64;
          const int kg = nt * 8 + g * 2;
          f32x4 e0 = *(const f32x4*)(erow + k + q * 8);
          f32x4 e1 = *(const f32x4*)(erow + k + q * 8 + 4);
          f16x8 fa = { (_Float16)e0[0], (_Float16)e0[1], (_Float16)e0[2], (_Float16)e0[3],
                       (_Float16)e1[0], (_Float16)e1[1], (_Float16)e1[2], (_Float16)e1[3] };
          f32x4 e2 = *(const f32x4*)(erow + k + 32 + q * 8);
          f32x4 e3 = *(const f32x4*)(erow + k + 32 + q * 8 + 4);
          f16x8 fb = { (_Float16)e2[0], (_Float16)e2[1], (_Float16)e2[2], (_Float16)e2[3],
                       (_Float16)e3[0], (_Float16)e3[1], (_Float16)e3[2], (_Float16)e3[3] };
          acc0 = MFMA(fa, LDSBF(0, kg), acc0);     acc1 = MFMA(fa, LDSBF(1, kg), acc1);
          acc0 = MFMA(fb, LDSBF(0, kg + 1), acc0); acc1 = MFMA(fb, LDSBF(1, kg + 1), acc1);
        }
      }
      // --- h0(s-1): streamed over this wave's 2 k-quarters ---
      if (s > 0) {
        const unsigned char* hp = h0buf + SLOTB(s - 1) + (size_t)brow * 1024 + nt * 512 + q * 16;
        HPART_STREAM(f0, s, hp, 16 + nt * 16);
      }
      ZWRITE();
      __syncthreads();
      if constexpr (!BIG) {
        if (s >= RING) { block_wait(f1, s - RING + 2, &gateF1); block_wait(f0, s - RING + 2, &gateF0); }
      }
      EPILOGUE(h0buf, SLOTB(s));
      __syncthreads();
      if (tid == 0)
        __hip_atomic_store(&f0[sub], s + 1, __ATOMIC_RELAXED, __HIP_MEMORY_SCOPE_AGENT);
    }
  } else {
    for (int j = 0; j < SLEN; ++j) {
      f32x4 acc0 = {0.f,0.f,0.f,0.f}, acc1 = {0.f,0.f,0.f,0.f};
      // --- h0'(j) FIRST (f0 has 1-step slack; off the f1->f1 cycle) ---
      {
        const unsigned char* hp = h0buf + SLOTB(j) + (size_t)brow * 1024 + nt * 512 + q * 16;
        HPART_STREAM(f0, j + 1, hp, nt * 16);
      }
      // --- h1(j-1): the f1-critical part, streamed, last before epilogue ---
      if (j > 0) {
        const unsigned char* hp = h1buf + SLOTB(j - 1) + (size_t)brow * 1024 + nt * 512 + q * 16;
        HPART_STREAM(f1, j, hp, 32 + nt * 16);
      }
      ZWRITE();
      __syncthreads();
      if constexpr (!BIG) {
        if (j >= RING) block_wait(f1, j - RING + 2, &gateF1);
      }
      EPILOGUE(h1buf, SLOTB(j));
      __syncthreads();
      if (tid == 0)
        __hip_atomic_store(&f1[sub], j + 1, __ATOMIC_RELAXED, __HIP_MEMORY_SCOPE_AGENT);
    }
  }
}

// ---- final FC: out[b] = sigmoid(h1(511) . fcw + fcb); h1 is e5m2-permuted ----
__global__ void fc_kernel(const unsigned char* __restrict__ h1slot,
                          const float* __restrict__ fcw, const float* __restrict__ fcb,
                          float* __restrict__ out) {
  __shared__ float part[512];
  const int tid = threadIdx.x, b = tid >> 3, q2 = tid & 7;
  const unsigned char* hr = h1slot + (size_t)b * 1024;
  float acc = 0.0f;
  for (int gg = 0; gg < 2; ++gg) {
    int g = q2 * 2 + gg;
    #pragma unroll
    for (int p = 0; p < 64; ++p) {
      unsigned by = hr[g * 64 + p];
      float hv = (float)__builtin_bit_cast(_Float16, (unsigned short)(by << 8));
      int qq = (p >> 4) & 3, hf = (p >> 3) & 1, jj = p & 7;
      acc += hv * fcw[g * 64 + hf * 32 + qq * 8 + jj];
    }
  }
  part[tid] = acc;
  __syncthreads();
  if (tid < BATCH) {
    float s = fcb[0];
    #pragma unroll
    for (int i = 0; i < 8; ++i) s += part[tid * 8 + i];
    out[tid] = 1.0f / (1.0f + __expf(-s));
  }
}

extern "C" void kernel_launch(void* const* d_in, const int* in_sizes, int n_in,
                              void* d_out, int out_size, void* d_ws, size_t ws_size,
                              hipStream_t stream) {
  (void)in_sizes; (void)n_in; (void)out_size;
  const int*   x   = (const int*)  d_in[0];
  const float* emb = (const float*)d_in[1];
  const float* Wx0 = (const float*)d_in[2];
  const float* bx0 = (const float*)d_in[3];
  const float* Wh0 = (const float*)d_in[4];
  const float* bh0 = (const float*)d_in[5];
  const float* Wx1 = (const float*)d_in[6];
  const float* bx1 = (const float*)d_in[7];
  const float* Wh1 = (const float*)d_in[8];
  const float* bh1 = (const float*)d_in[9];
  const float* fcw = (const float*)d_in[10];
  const float* fcb = (const float*)d_in[11];
  float* out = (float*)d_out;

  char* ws = (char*)d_ws;
  int* f0 = (int*)(ws);
  int* f1 = (int*)(ws + 512);

  const size_t need_big = 4096 + 2 * HBUF_BIG + XE_BYTES;   // ~80.1 MiB
  const size_t need_sml = 4096 + 2 * HBUF_SML + XE_BYTES;   // ~17.1 MiB
  const int big    = (ws_size >= need_big) ? 1 : 0;
  const size_t hbytes = big ? HBUF_BIG : HBUF_SML;
  unsigned char* h0buf = (unsigned char*)(ws + 4096);
  unsigned char* h1buf = (unsigned char*)(ws + 4096 + hbytes);
  unsigned char* xe    = (unsigned char*)(ws + 4096 + 2 * hbytes);
  const int use_xe = (big || ws_size >= need_sml) ? 1 : 0;

  hipMemsetAsync(d_ws, 0, 4096, stream);   // flags only
  if (use_xe) {
    const int groups = SLEN * BATCH * (EDIM / 8);
    xe_gather<<<(groups + 255) / 256, 256, 0, stream>>>(x, emb, xe);
  }
  if (big) {
    lstm_persistent<1><<<NBLK, 512, 0, stream>>>(x, emb, Wx0, bx0, Wh0, bh0,
                                                 Wx1, bx1, Wh1, bh1,
                                                 xe, use_xe, h0buf, h1buf, f0, f1);
    fc_kernel<<<1, 512, 0, stream>>>(h1buf + (size_t)(SLEN - 1) * HSLOT, fcw, fcb, out);
  } else {
    lstm_persistent<0><<<NBLK, 512, 0, stream>>>(x, emb, Wx0, bx0, Wh0, bh0,
                                                 Wx1, bx1, Wh1, bh1,
                                                 xe, use_xe, h0buf, h1buf, f0, f1);
    fc_kernel<<<1, 512, 0, stream>>>(h1buf + (size_t)((SLEN - 1) & (RING - 1)) * HSLOT, fcw, fcb, out);
  }
}

// Round 18
// 2889.492 us; speedup vs baseline: 1.1415x; 1.1415x over previous
//
#include <hip/hip_runtime.h>

// ---------------- problem constants ----------------
#define BATCH 64
#define SLEN  512
#define EDIM  512
#define HDIM  1024
#define NBLK  256
#define HALF  128                // blocks per layer group
#define ZR    32                 // z-rows per block = 4 gates x 8 h-cols
#define ZST   68                 // zbuf batch-row stride (2 nt-partials of 34)
#define HSLOT 65536              // bytes per h slot (64 x 1024 e5m2)
#define XROWB 512                // xe row bytes (512 e5m2)
#define RING  8                  // fallback ring depth

#define XE_BYTES ((size_t)SLEN * BATCH * XROWB)         // 16 MiB
#define HBUF_BIG ((size_t)SLEN * HSLOT)                 // 32 MiB per layer
#define HBUF_SML ((size_t)RING * HSLOT)                 // 512 KiB per layer

typedef _Float16 f16x8 __attribute__((ext_vector_type(8)));
typedef float  f32x4  __attribute__((ext_vector_type(4)));
typedef unsigned u32x4 __attribute__((ext_vector_type(4)));
typedef unsigned u32x2 __attribute__((ext_vector_type(2)));

__device__ __forceinline__ float sigm(float x) { return 1.0f / (1.0f + __expf(-x)); }
__device__ __forceinline__ float tanhfast(float x) {
  float e = __expf(-2.0f * __builtin_fabsf(x));
  float r = (1.0f - e) / (1.0f + e);
  return x < 0.0f ? -r : r;
}

// f32 -> e5m2 byte (via f16, round mantissa-half-up)
__device__ __forceinline__ unsigned enc_e5m2(float v) {
  unsigned short hb = __builtin_bit_cast(unsigned short, (_Float16)v);
  return ((unsigned)hb + 0x80u) >> 8;
}

// 4 e5m2 bytes (one dword) -> 2 dwords of f16 pairs (byte<<8 expand via v_perm)
__device__ __forceinline__ void dec4(unsigned w, unsigned &lo, unsigned &hi) {
  lo = __builtin_amdgcn_perm(w, 0u, 0x05000400u);   // [0,b0, 0,b1]
  hi = __builtin_amdgcn_perm(w, 0u, 0x07000600u);   // [0,b2, 0,b3]
}

// 16 e5m2 bytes -> two f16x8 fragments (bytes 0-7 = k..k+8 half0, 8-15 = half1)
__device__ __forceinline__ void dec16(u32x4 d, f16x8 &fa, f16x8 &fb) {
  union { unsigned u[4]; f16x8 v; } A, B;
  dec4(d[0], A.u[0], A.u[1]); dec4(d[1], A.u[2], A.u[3]);
  dec4(d[2], B.u[0], B.u[1]); dec4(d[3], B.u[2], B.u[3]);
  fa = A.v; fb = B.v;
}

// 8B write-through store (L3-visible after vmcnt drain; never dirty in L2)
__device__ __forceinline__ void st8_wt(unsigned char* p, unsigned d0, unsigned d1) {
  u32x2 v = {d0, d1};
  asm volatile("global_store_dwordx2 %0, %1, off sc0 sc1" :: "v"(p), "v"(v) : "memory");
}

// 16B loads: BIG = normal (L2-multicast); ring mode = L2-bypassing atomics
__device__ __forceinline__ u32x4 ald16b(const unsigned char* p) {
  union { unsigned long long q[2]; u32x4 v; } u;
  u.q[0] = __hip_atomic_load((const unsigned long long*)p,       __ATOMIC_RELAXED, __HIP_MEMORY_SCOPE_AGENT);
  u.q[1] = __hip_atomic_load((const unsigned long long*)(p + 8), __ATOMIC_RELAXED, __HIP_MEMORY_SCOPE_AGENT);
  return u.v;
}
template<int BIG>
__device__ __forceinline__ u32x4 hload16(const unsigned char* p) {
  if constexpr (BIG) return *(const u32x4*)p;
  else return ald16b(p);
}

// Block-level wait: wave 0 polls 128 global flags, LDS gate for waves 1-7.
__device__ __forceinline__ void block_wait(const int* f, int target, int* gate) {
  if (target <= 0) return;
  if ((threadIdx.x >> 6) == 0) {
    if (__hip_atomic_load(gate, __ATOMIC_RELAXED, __HIP_MEMORY_SCOPE_WORKGROUP) < target) {
      const int l = threadIdx.x & 63;
      int tries = 0;
      while (true) {
        int v0 = __hip_atomic_load(f + l,      __ATOMIC_RELAXED, __HIP_MEMORY_SCOPE_AGENT);
        int v1 = __hip_atomic_load(f + l + 64, __ATOMIC_RELAXED, __HIP_MEMORY_SCOPE_AGENT);
        if (__all((v0 >= target) && (v1 >= target))) break;
        __builtin_amdgcn_s_sleep(1);
        if (++tries > (1 << 21)) break;   // anti-hang safety net
      }
      if (l == 0)
        __hip_atomic_fetch_max(gate, target, __ATOMIC_RELEASE, __HIP_MEMORY_SCOPE_WORKGROUP);
    }
  } else {
    int tries = 0;
    while (__hip_atomic_load(gate, __ATOMIC_ACQUIRE, __HIP_MEMORY_SCOPE_WORKGROUP) < target) {
      __builtin_amdgcn_s_sleep(1);
      if (++tries > (1 << 21)) break;
    }
  }
}

// ---- xe = e5m2(emb[x]) laid out [t][b][512B], 64-col-group permuted ----
__global__ void xe_gather(const int* __restrict__ x, const float* __restrict__ emb,
                          unsigned char* __restrict__ xe) {
  int g = blockIdx.x * blockDim.x + threadIdx.x;
  if (g >= SLEN * BATCH * (EDIM / 8)) return;
  int e8 = g & 63, bt = g >> 6;
  int b = bt & 63, t = bt >> 6;
  int tok = x[b * SLEN + t];
  const float* er = emb + (size_t)tok * EDIM + e8 * 8;
  f32x4 v0 = *(const f32x4*)er, v1 = *(const f32x4*)(er + 4);
  unsigned d0 = enc_e5m2(v0[0]) | (enc_e5m2(v0[1]) << 8) | (enc_e5m2(v0[2]) << 16) | (enc_e5m2(v0[3]) << 24);
  unsigned d1 = enc_e5m2(v1[0]) | (enc_e5m2(v1[1]) << 8) | (enc_e5m2(v1[2]) << 16) | (enc_e5m2(v1[3]) << 24);
  int pb = (e8 >> 3) * 64 + (e8 & 3) * 16 + ((e8 >> 2) & 1) * 8;
  *(u32x2*)(xe + ((size_t)t * BATCH + b) * XROWB + pb) = (u32x2){d0, d1};
}

#define MFMA(a, b, c) __builtin_amdgcn_mfma_f32_16x16x32_f16(a, b, c, 0, 0, 0)
// fragment-major B: fragment (t, kg) at ((t*64+kg)*64 + lane)*16 — a wave's
// read is one contiguous 1KB burst (R14-measured: conflicts 2.5e8 -> 1.7e7).
// lane ln holds B[k = kg*32 + (ln>>4)*8 .. +8][zcol = t*16 + (ln&15)].
#define LDSBF(t, kg) (*(const f16x8*)(&Ws[(size_t)((((t) * 64 + (kg)) * 64 + lane)) * 16]))

// Persistent skewed 2-layer LSTM. e5m2 activations (halved A-load lines, R12),
// f16 fragment-major LDS weights (R14), L1 h0-first cycle order (R13),
// write-once h slots + L2-multicast loads (R4), wt-stores + flag dataflow (R5).
// FINAL: best measured configuration, 2892 us (7.3x over R1 baseline).
template<int BIG>
__global__ __launch_bounds__(512, 2) void lstm_persistent(
    const int* __restrict__ x, const float* __restrict__ emb,
    const float* __restrict__ Wx0, const float* __restrict__ bx0,
    const float* __restrict__ Wh0, const float* __restrict__ bh0,
    const float* __restrict__ Wx1, const float* __restrict__ bx1,
    const float* __restrict__ Wh1, const float* __restrict__ bh1,
    const unsigned char* __restrict__ xe, int use_xe,
    unsigned char* h0buf, unsigned char* h1buf, int* f0, int* f1)
{
  __shared__ __align__(16) unsigned char Ws[2 * 64 * 64 * 16];  // 128 KiB
  __shared__ float zbuf[BATCH * ZST];                           // 17 KiB
  __shared__ float bias[ZR];
  __shared__ int gateF0, gateF1;

  const int tid   = threadIdx.x;
  const int wg    = blockIdx.x;
  const int layer = wg >> 7;
  const int sub   = wg & (HALF - 1);

  if (tid == 0) { gateF0 = 0; gateF1 = 0; }

  // ---- stage weights into fragment-major LDS (linear 16B writes) ----
  {
    const int KG = layer ? 64 : 48;          // k-groups of 32 f16 elems
    for (int idx = tid; idx < 2 * KG * 64; idx += 512) {
      int t  = idx / (KG * 64);
      int r  = idx - t * (KG * 64);
      int kg = r >> 6, ln = r & 63;
      int n  = t * 16 + (ln & 15);           // z-col 0..31
      int grow = (n >> 3) * HDIM + sub * 8 + (n & 7);
      int k  = kg * 32 + (ln >> 4) * 8;
      const float* src;
      if (layer == 0) src = (k < EDIM) ? (Wx0 + (size_t)grow * EDIM + k)
                                       : (Wh0 + (size_t)grow * HDIM + (k - EDIM));
      else            src = (k < HDIM) ? (Wx1 + (size_t)grow * HDIM + k)
                                       : (Wh1 + (size_t)grow * HDIM + (k - HDIM));
      f32x4 v0 = *(const f32x4*)src, v1 = *(const f32x4*)(src + 4);
      f16x8 o = { (_Float16)v0[0], (_Float16)v0[1], (_Float16)v0[2], (_Float16)v0[3],
                  (_Float16)v1[0], (_Float16)v1[1], (_Float16)v1[2], (_Float16)v1[3] };
      *(f16x8*)(&Ws[(size_t)((t * 64 + kg) * 64 + ln) * 16]) = o;
    }
    if (tid < ZR) {
      int grow = (tid >> 3) * HDIM + sub * 8 + (tid & 7);
      bias[tid] = layer ? (bx1[grow] + bh1[grow]) : (bx0[grow] + bh0[grow]);
    }
  }
  __syncthreads();

  const int lane = tid & 63, wave = tid >> 6;
  const int mrow = lane & 15;
  const int q    = lane >> 4;
  const int mt   = wave >> 1, nt = wave & 1;   // 4 batch tiles x 2 contiguous K-halves
  const int brow = mt * 16 + mrow;
  const int bg = tid >> 3, jl = tid & 7;
  const int zrow = mt * 16 + q * 4;
  const int pbase = (sub >> 3) * 64 + (sub & 3) * 16 + ((sub >> 2) & 1) * 8;

  float cst = 0.0f;

#define SLOTB(s) ((size_t)(BIG ? (s) : ((s) & (RING - 1))) * HSLOT)

#define ZWRITE()                                                                  \
  do {                                                                            \
    _Pragma("unroll")                                                             \
    for (int r = 0; r < 4; ++r) {                                                 \
      zbuf[(zrow + r) * ZST + nt * 34 + mrow]      = acc0[r];                     \
      zbuf[(zrow + r) * ZST + nt * 34 + 16 + mrow] = acc1[r];                     \
    }                                                                             \
  } while (0)

#define EPILOGUE(hdst, slotExpr)                                                  \
  do {                                                                            \
    float zf = zbuf[bg*ZST +      jl] + zbuf[bg*ZST + 34 +      jl] + bias[     jl]; \
    float zi = zbuf[bg*ZST +  8 + jl] + zbuf[bg*ZST + 34 +  8 + jl] + bias[ 8 + jl]; \
    float zg = zbuf[bg*ZST + 16 + jl] + zbuf[bg*ZST + 34 + 16 + jl] + bias[16 + jl]; \
    float zo = zbuf[bg*ZST + 24 + jl] + zbuf[bg*ZST + 34 + 24 + jl] + bias[24 + jl]; \
    float fg = sigm(zf), ig = sigm(zi), gg = tanhfast(zg), og = sigm(zo);         \
    cst = fg * cst + ig * gg;                                                     \
    unsigned by = enc_e5m2(og * tanhfast(cst));                                   \
    unsigned w0 = by | (((unsigned)__shfl_xor((int)by, 1, 64) & 0xFFu) << 8);     \
    w0 |= ((unsigned)__shfl_xor((int)w0, 2, 64) & 0xFFFFu) << 16;                 \
    unsigned dd1 = (unsigned)__shfl_xor((int)w0, 4, 64);                          \
    if (jl == 0)                                                                  \
      st8_wt(hdst + (slotExpr) + (size_t)bg * 1024 + pbase, w0, dd1);             \
    asm volatile("s_waitcnt vmcnt(0)" ::: "memory");                              \
  } while (0)

  if (layer == 0) {
    for (int s = 0; s < SLEN; ++s) {
      f32x4 acc0 = {0.f,0.f,0.f,0.f}, acc1 = {0.f,0.f,0.f,0.f};
      // --- xe part: no cross-block dep, runs before the f0 wait ---
      if (use_xe) {
        const unsigned char* aX = xe + ((size_t)s * BATCH + brow) * XROWB + nt * 256 + q * 16;
        #pragma unroll
        for (int g = 0; g < 4; ++g) {
          f16x8 fa, fb; dec16(*(const u32x4*)(aX + g * 64), fa, fb);
          const int kg = nt * 8 + g * 2;
          acc0 = MFMA(fa, LDSBF(0, kg), acc0);     acc1 = MFMA(fa, LDSBF(1, kg), acc1);
          acc0 = MFMA(fb, LDSBF(0, kg + 1), acc0); acc1 = MFMA(fb, LDSBF(1, kg + 1), acc1);
        }
      } else {
        const int tok = x[brow * SLEN + s];
        const float* erow = emb + (size_t)tok * EDIM;
        #pragma unroll
        for (int g = 0; g < 4; ++g) {
          const int k = nt * 256 + g * 64;
          const int kg = nt * 8 + g * 2;
          f32x4 e0 = *(const f32x4*)(erow + k + q * 8);
          f32x4 e1 = *(const f32x4*)(erow + k + q * 8 + 4);
          f16x8 fa = { (_Float16)e0[0], (_Float16)e0[1], (_Float16)e0[2], (_Float16)e0[3],
                       (_Float16)e1[0], (_Float16)e1[1], (_Float16)e1[2], (_Float16)e1[3] };
          f32x4 e2 = *(const f32x4*)(erow + k + 32 + q * 8);
          f32x4 e3 = *(const f32x4*)(erow + k + 32 + q * 8 + 4);
          f16x8 fb = { (_Float16)e2[0], (_Float16)e2[1], (_Float16)e2[2], (_Float16)e2[3],
                       (_Float16)e3[0], (_Float16)e3[1], (_Float16)e3[2], (_Float16)e3[3] };
          acc0 = MFMA(fa, LDSBF(0, kg), acc0);     acc1 = MFMA(fa, LDSBF(1, kg), acc1);
          acc0 = MFMA(fb, LDSBF(0, kg + 1), acc0); acc1 = MFMA(fb, LDSBF(1, kg + 1), acc1);
        }
      }
      // --- h0(s-1): the recurrence-critical part ---
      if (s > 0) {
        block_wait(f0, s, &gateF0);
        const unsigned char* hp = h0buf + SLOTB(s - 1) + (size_t)brow * 1024 + nt * 512 + q * 16;
        #pragma unroll
        for (int g = 0; g < 8; ++g) {
          f16x8 fa, fb; dec16(hload16<BIG>(hp + g * 64), fa, fb);
          const int kg = 16 + nt * 16 + g * 2;   // EDIM/32 = 16 offset
          acc0 = MFMA(fa, LDSBF(0, kg), acc0);     acc1 = MFMA(fa, LDSBF(1, kg), acc1);
          acc0 = MFMA(fb, LDSBF(0, kg + 1), acc0); acc1 = MFMA(fb, LDSBF(1, kg + 1), acc1);
        }
      }
      ZWRITE();
      __syncthreads();
      if constexpr (!BIG) {
        if (s >= RING) { block_wait(f1, s - RING + 2, &gateF1); block_wait(f0, s - RING + 2, &gateF0); }
      }
      EPILOGUE(h0buf, SLOTB(s));
      __syncthreads();
      if (tid == 0)
        __hip_atomic_store(&f0[sub], s + 1, __ATOMIC_RELAXED, __HIP_MEMORY_SCOPE_AGENT);
    }
  } else {
    for (int j = 0; j < SLEN; ++j) {
      f32x4 acc0 = {0.f,0.f,0.f,0.f}, acc1 = {0.f,0.f,0.f,0.f};
      // --- h0'(j) FIRST (f0 has 1-step slack; off the f1->f1 cycle) ---
      block_wait(f0, j + 1, &gateF0);
      {
        const unsigned char* hp = h0buf + SLOTB(j) + (size_t)brow * 1024 + nt * 512 + q * 16;
        #pragma unroll
        for (int g = 0; g < 8; ++g) {
          f16x8 fa, fb; dec16(hload16<BIG>(hp + g * 64), fa, fb);
          const int kg = nt * 16 + g * 2;
          acc0 = MFMA(fa, LDSBF(0, kg), acc0);     acc1 = MFMA(fa, LDSBF(1, kg), acc1);
          acc0 = MFMA(fb, LDSBF(0, kg + 1), acc0); acc1 = MFMA(fb, LDSBF(1, kg + 1), acc1);
        }
      }
      // --- h1(j-1): the f1-critical part, last before epilogue ---
      if (j > 0) {
        block_wait(f1, j, &gateF1);
        const unsigned char* hp = h1buf + SLOTB(j - 1) + (size_t)brow * 1024 + nt * 512 + q * 16;
        #pragma unroll
        for (int g = 0; g < 8; ++g) {
          f16x8 fa, fb; dec16(hload16<BIG>(hp + g * 64), fa, fb);
          const int kg = 32 + nt * 16 + g * 2;   // HDIM/32 = 32 offset
          acc0 = MFMA(fa, LDSBF(0, kg), acc0);     acc1 = MFMA(fa, LDSBF(1, kg), acc1);
          acc0 = MFMA(fb, LDSBF(0, kg + 1), acc0); acc1 = MFMA(fb, LDSBF(1, kg + 1), acc1);
        }
      }
      ZWRITE();
      __syncthreads();
      if constexpr (!BIG) {
        if (j >= RING) block_wait(f1, j - RING + 2, &gateF1);
      }
      EPILOGUE(h1buf, SLOTB(j));
      __syncthreads();
      if (tid == 0)
        __hip_atomic_store(&f1[sub], j + 1, __ATOMIC_RELAXED, __HIP_MEMORY_SCOPE_AGENT);
    }
  }
}

// ---- final FC: out[b] = sigmoid(h1(511) . fcw + fcb); h1 is e5m2-permuted ----
__global__ void fc_kernel(const unsigned char* __restrict__ h1slot,
                          const float* __restrict__ fcw, const float* __restrict__ fcb,
                          float* __restrict__ out) {
  __shared__ float part[512];
  const int tid = threadIdx.x, b = tid >> 3, q2 = tid & 7;
  const unsigned char* hr = h1slot + (size_t)b * 1024;
  float acc = 0.0f;
  for (int gg = 0; gg < 2; ++gg) {
    int g = q2 * 2 + gg;
    #pragma unroll
    for (int p = 0; p < 64; ++p) {
      unsigned by = hr[g * 64 + p];
      float hv = (float)__builtin_bit_cast(_Float16, (unsigned short)(by << 8));
      int qq = (p >> 4) & 3, hf = (p >> 3) & 1, jj = p & 7;
      acc += hv * fcw[g * 64 + hf * 32 + qq * 8 + jj];
    }
  }
  part[tid] = acc;
  __syncthreads();
  if (tid < BATCH) {
    float s = fcb[0];
    #pragma unroll
    for (int i = 0; i < 8; ++i) s += part[tid * 8 + i];
    out[tid] = 1.0f / (1.0f + __expf(-s));
  }
}

extern "C" void kernel_launch(void* const* d_in, const int* in_sizes, int n_in,
                              void* d_out, int out_size, void* d_ws, size_t ws_size,
                              hipStream_t stream) {
  (void)in_sizes; (void)n_in; (void)out_size;
  const int*   x   = (const int*)  d_in[0];
  const float* emb = (const float*)d_in[1];
  const float* Wx0 = (const float*)d_in[2];
  const float* bx0 = (const float*)d_in[3];
  const float* Wh0 = (const float*)d_in[4];
  const float* bh0 = (const float*)d_in[5];
  const float* Wx1 = (const float*)d_in[6];
  const float* bx1 = (const float*)d_in[7];
  const float* Wh1 = (const float*)d_in[8];
  const float* bh1 = (const float*)d_in[9];
  const float* fcw = (const float*)d_in[10];
  const float* fcb = (const float*)d_in[11];
  float* out = (float*)d_out;

  char* ws = (char*)d_ws;
  int* f0 = (int*)(ws);
  int* f1 = (int*)(ws + 512);

  const size_t need_big = 4096 + 2 * HBUF_BIG + XE_BYTES;   // ~80.1 MiB
  const size_t need_sml = 4096 + 2 * HBUF_SML + XE_BYTES;   // ~17.1 MiB
  const int big    = (ws_size >= need_big) ? 1 : 0;
  const size_t hbytes = big ? HBUF_BIG : HBUF_SML;
  unsigned char* h0buf = (unsigned char*)(ws + 4096);
  unsigned char* h1buf = (unsigned char*)(ws + 4096 + hbytes);
  unsigned char* xe    = (unsigned char*)(ws + 4096 + 2 * hbytes);
  const int use_xe = (big || ws_size >= need_sml) ? 1 : 0;

  hipMemsetAsync(d_ws, 0, 4096, stream);   // flags only
  if (use_xe) {
    const int groups = SLEN * BATCH * (EDIM / 8);
    xe_gather<<<(groups + 255) / 256, 256, 0, stream>>>(x, emb, xe);
  }
  if (big) {
    lstm_persistent<1><<<NBLK, 512, 0, stream>>>(x, emb, Wx0, bx0, Wh0, bh0,
                                                 Wx1, bx1, Wh1, bh1,
                                                 xe, use_xe, h0buf, h1buf, f0, f1);
    fc_kernel<<<1, 512, 0, stream>>>(h1buf + (size_t)(SLEN - 1) * HSLOT, fcw, fcb, out);
  } else {
    lstm_persistent<0><<<NBLK, 512, 0, stream>>>(x, emb, Wx0, bx0, Wh0, bh0,
                                                 Wx1, bx1, Wh1, bh1,
                                                 xe, use_xe, h0buf, h1buf, f0, f1);
    fc_kernel<<<1, 512, 0, stream>>>(h1buf + (size_t)((SLEN - 1) & (RING - 1)) * HSLOT, fcw, fcb, out);
  }
}